// Round 15
// baseline (106.836 us; speedup 1.0000x reference)
//
#include <hip/hip_runtime.h>
#include <stdint.h>

// ---------------------------------------------------------------------------
// TopK: scores = (embs @ scorer)/sum(scorer) + mask; top-k rows; out = rows^T
// Ordering matches numpy/OpenBLAS sgemv_t fp32 bits exactly (verified
// R3/R5/R6/R8/R10/R11/R13/R14, absmax=0): per row, 8 mod-8 fma chains (chain
// c sums elements c, c+8, ... ascending), reduced as
// ((L0+L4)+(L1+L5))+((L2+L6)+(L3+L7)), realized as 8 threads/row +
// shfl_xor pair-sums (bitwise-commutative adds).
// R15: selection collapsed to ONE kernel with ZERO cross-block sync.
// Lessons: R9/R10/R12 = any multi-block wait costs 10+us; R11 = even narrow
// publish/poll costs us. With keys L2/L3-hot, redundant recomputation is
// cheaper than synchronization:
//   kSel (8 blocks x 1024): each block redundantly builds the FULL hist
//   (2 LDS sub-hists), extracts bucket B (verified suffix-scan), redundantly
//   compacts ALL keys into its own LDS candidate list (per-wave slices,
//   deterministic, no atomics), then ranks its OWN 1/8 of candidates
//   (verified k4 wave body) -> disjoint oidx writes.
// Pipeline: k1 (R11 verbatim) -> kSel -> k5. 3 kernels, 2 gaps.
// d_out holds keys; k5 overwrites all of d_out. ws: oidx (8KB) only.
// ---------------------------------------------------------------------------

#define NBINS 8192   // 13-bit radix: sign + exp(8) + mantissa(4)
#define BIN_SHIFT 19
#define CAP 4096     // candidates: k + boundary bin (~600) << CAP
#define SELB 8       // kSel blocks

__device__ __forceinline__ uint32_t f2key(float f) {
  uint32_t b = __float_as_uint(f);
  return (b & 0x80000000u) ? ~b : (b | 0x80000000u);
}

// ---- kernel 1: 32 rows/block, 8 threads/row (one mod-8 chain each) --------
// R11 verbatim (best k1: R13 occupancy probe neutral, R14 1-phase regressed).
__global__ __launch_bounds__(256) void k1_scores(
    const float* __restrict__ embs, const float* __restrict__ mask,
    const float* __restrict__ scorer,
    uint32_t* __restrict__ keys, int N) {
  __shared__ float tile[32 * 132];
  __shared__ float sw[256];
  __shared__ float Ssh;
  int t = threadIdx.x;
  int r0 = blockIdx.x * 32;
  sw[t] = scorer[t];  // F == 256
  __syncthreads();
  if (t < 64) {
    double s = 0.0;
    for (int j = t; j < 256; j += 64) s += (double)sw[j];
#pragma unroll
    for (int off = 32; off >= 1; off >>= 1) s += __shfl_xor(s, off, 64);
    if (t == 0) Ssh = (float)s;  // f64 sum: order-independent at f32 grain
  }
  __syncthreads();
  float S = Ssh;
  int r = t >> 3, c = t & 7;
  float acc = 0.f;
  const float4* e4 = (const float4*)embs;
#pragma unroll
  for (int ch = 0; ch < 2; ++ch) {
    if (ch) __syncthreads();  // previous chunk's LDS reads complete
#pragma unroll
    for (int m = 0; m < 4; ++m) {      // 4*256 = 1024 f4 = 32 rows x 32 f4
      int flat = m * 256 + t;
      int rr = flat >> 5;              // 0..31
      int cc4 = flat & 31;             // 0..31
      int row = r0 + rr;
      float4 v = make_float4(0.f, 0.f, 0.f, 0.f);
      if (row < N) v = e4[(size_t)row * 64 + ch * 32 + cc4];  // 512B segs
      float* dst = &tile[rr * 132 + cc4 * 4];
      dst[0] = v.x; dst[1] = v.y; dst[2] = v.z; dst[3] = v.w;
    }
    __syncthreads();
#pragma unroll
    for (int sl = 0; sl < 16; ++sl) {  // ascending k within the chain
      acc = fmaf(tile[r * 132 + c + 8 * sl], sw[ch * 128 + c + 8 * sl], acc);
    }
  }
  // exact OpenBLAS bracket via commutative pair-sums (lanes stay in-row):
  float m1 = acc + __shfl_xor(acc, 4, 64);  // L_c + L_{c+4}
  float p1 = m1 + __shfl_xor(m1, 1, 64);    // (m0+m1) / (m2+m3)
  float dot = p1 + __shfl_xor(p1, 2, 64);   // ((m0+m1)+(m2+m3))
  int row = r0 + r;
  if (c == 0 && row < N) {
    float score = dot / S + mask[row];
    keys[row] = f2key(score);
  }
}

// ---- kernel Sel: per-block redundant hist+find+compact; ranked 1/8 each ---
__global__ __launch_bounds__(1024) void kSel(
    const uint32_t* __restrict__ keys, uint32_t* __restrict__ oidx,
    int N, int k) {
  __shared__ uint32_t shm[2 * NBINS];  // 64KB: sub-hists, then lk/li
  __shared__ uint32_t wtot[16], wsuf[16], scnt[16], sbase[16];
  __shared__ uint32_t sB, sC;
  int t = threadIdx.x, bid = blockIdx.x;
  int lane = t & 63, wave = t >> 6;
  uint32_t* h0 = shm;
  uint32_t* h1 = shm + NBINS;

  // --- full redundant histogram (every block, all N keys) ---
  for (int i = t; i < 2 * NBINS; i += 1024) shm[i] = 0u;
  __syncthreads();
  uint32_t* hh = ((t >> 7) & 1) ? h1 : h0;
  int n4 = N >> 2;
  const uint4* q4 = (const uint4*)keys;
  for (int i = t; i < n4; i += 1024) {
    uint4 v = q4[i];
    atomicAdd(&hh[v.x >> BIN_SHIFT], 1u);
    atomicAdd(&hh[v.y >> BIN_SHIFT], 1u);
    atomicAdd(&hh[v.z >> BIN_SHIFT], 1u);
    atomicAdd(&hh[v.w >> BIN_SHIFT], 1u);
  }
  for (int i = (n4 << 2) + t; i < N; i += 1024)
    atomicAdd(&hh[keys[i] >> BIN_SHIFT], 1u);
  __syncthreads();

  // --- bucket B: 8 bins/thread merge + suffix scan (verified logic) ---
  uint32_t rb[8];
  uint32_t p8 = 0;
#pragma unroll
  for (int j = 0; j < 8; ++j) {
    int bin = t * 8 + j;
    uint32_t s = h0[bin] + h1[bin];
    rb[j] = s;
    p8 += s;
  }
  uint32_t x = p8;  // wave-internal inclusive suffix scan
#pragma unroll
  for (int off = 1; off < 64; off <<= 1) {
    uint32_t v = __shfl_down(x, off, 64);
    if (lane + off < 64) x += v;
  }
  if (lane == 0) wtot[wave] = x;
  __syncthreads();
  if (t < 16) {
    uint32_t y = wtot[t];
#pragma unroll
    for (int off = 1; off < 16; off <<= 1) {
      uint32_t v = __shfl_down(y, off, 64);
      if (t + off < 16) y += v;
    }
    wsuf[t] = y - wtot[t];  // sum of waves after t
  }
  __syncthreads();
  uint32_t St = x + wsuf[wave];  // count(bin >= 8t)
  uint32_t above = St - p8;      // count(bin >= 8(t+1))
  if (above < (uint32_t)k && St >= (uint32_t)k) {  // unique thread
    uint32_t cum = above;
#pragma unroll
    for (int jj = 7; jj >= 0; --jj) {
      if (cum + rb[jj] >= (uint32_t)k) { sB = (uint32_t)(t * 8 + jj); break; }
      cum += rb[jj];
    }
  }
  __syncthreads();  // sB ready; hist reads done -> shm reusable
  uint32_t B = sB;

  // --- compact ALL keys into LDS, per-wave slices (deterministic) ---
  int per = (N + 15) >> 4;  // per wave
  int lo = wave * per;
  int hi = lo + per; if (hi > N) hi = N;
  // pass a: count
  uint32_t cnt = 0;
  for (int ib = lo; ib < hi; ib += 64) {
    int i = ib + lane;
    cnt += (i < hi && (keys[i] >> BIN_SHIFT) >= B) ? 1u : 0u;
  }
#pragma unroll
  for (int off = 32; off >= 1; off >>= 1) cnt += __shfl_xor(cnt, off, 64);
  if (lane == 0) scnt[wave] = cnt;
  __syncthreads();
  if (t == 0) {
    uint32_t tot = 0;
#pragma unroll
    for (int w = 0; w < 16; ++w) { sbase[w] = tot; tot += scnt[w]; }
    sC = (tot > CAP) ? CAP : tot;
  }
  __syncthreads();
  uint32_t* lk = shm;        // reuse hist LDS
  uint32_t* li = shm + CAP;
  // pass b: append in index order (identical list in every block)
  uint32_t pos = sbase[wave];
  for (int ib = lo; ib < hi; ib += 64) {
    int i = ib + lane;
    bool pred = (i < hi) && ((keys[i] >> BIN_SHIFT) >= B);
    unsigned long long ball = __ballot(pred);
    uint32_t pre = (uint32_t)__popcll(ball & ((1ull << lane) - 1ull));
    if (pred) {
      uint32_t p = pos + pre;
      if (p < CAP) { lk[p] = keys[i]; li[p] = (uint32_t)i; }
    }
    pos += (uint32_t)__popcll(ball);
  }
  __syncthreads();
  uint32_t C = sC;

  // --- rank own 1/8 of candidates (verified k4 wave body) ---
  uint32_t chunk = (C + SELB - 1) / SELB;
  uint32_t rlo = (uint32_t)bid * chunk;
  uint32_t rhi = rlo + chunk; if (rhi > C) rhi = C;
  for (uint32_t g0 = rlo + (uint32_t)wave * 4u; g0 < rhi; g0 += 64u) {
    uint32_t mk[4], mi[4], cq[4];
#pragma unroll
    for (int q = 0; q < 4; ++q) {
      uint32_t g = g0 + q;
      bool valid = g < rhi;
      mk[q] = valid ? lk[g] : 0u;
      mi[q] = valid ? li[g] : 0xFFFFFFFFu;
      cq[q] = 0u;
    }
    for (uint32_t j = lane; j < C; j += 64u) {
      uint32_t kj = lk[j], ij = li[j];
#pragma unroll
      for (int q = 0; q < 4; ++q)
        cq[q] += (kj > mk[q] || (kj == mk[q] && ij < mi[q])) ? 1u : 0u;
    }
#pragma unroll
    for (int q = 0; q < 4; ++q) {
#pragma unroll
      for (int off = 32; off >= 1; off >>= 1) cq[q] += __shfl_xor(cq[q], off, 64);
    }
    if (lane == 0) {
#pragma unroll
      for (int q = 0; q < 4; ++q) {
        uint32_t g = g0 + q;
        if (g < rhi && cq[q] < (uint32_t)k) oidx[cq[q]] = mi[q];
      }
    }
  }
}

// ---- kernel 5: gather + transpose; 16 ranks x 128 feats per block ----------
__global__ __launch_bounds__(256) void k5_gather(
    const float* __restrict__ embs, const uint32_t* __restrict__ oidx,
    float* __restrict__ out, int k) {
  __shared__ float tile[16 * 132];
  __shared__ uint32_t sidx[16];
  int t = threadIdx.x;
  int r0 = blockIdx.x * 16;
  int fb = blockIdx.y * 128;
  if (t < 16) sidx[t] = (r0 + t < k) ? oidx[r0 + t] : 0u;
  __syncthreads();
  const float4* e4 = (const float4*)embs;
#pragma unroll
  for (int m = 0; m < 2; ++m) {      // 2*256 = 512 f4 = 16 rows x 32 f4
    int flat = m * 256 + t;
    int rr = flat >> 5;
    int cc4 = flat & 31;
    float4 v = e4[(size_t)sidx[rr] * 64 + (fb >> 2) + cc4];
    float* dst = &tile[rr * 132 + cc4 * 4];
    dst[0] = v.x; dst[1] = v.y; dst[2] = v.z; dst[3] = v.w;
  }
  __syncthreads();
  int fl = t >> 1;   // 0..127 local feature
  int rq = t & 1;    // which 8-rank group
  float v[8];
#pragma unroll
  for (int i = 0; i < 8; ++i) v[i] = tile[(rq * 8 + i) * 132 + fl];
  size_t obase = (size_t)(fb + fl) * k + r0 + rq * 8;
  if (((k & 3) == 0) && (r0 + rq * 8 + 7 < k)) {
    *(float4*)(out + obase) = make_float4(v[0], v[1], v[2], v[3]);
    *(float4*)(out + obase + 4) = make_float4(v[4], v[5], v[6], v[7]);
  } else {
#pragma unroll
    for (int i = 0; i < 8; ++i)
      if (r0 + rq * 8 + i < k) out[obase + i] = v[i];
  }
}

extern "C" void kernel_launch(void* const* d_in, const int* in_sizes, int n_in,
                              void* d_out, int out_size, void* d_ws, size_t ws_size,
                              hipStream_t stream) {
  const float* embs = (const float*)d_in[0];
  const float* mask = (const float*)d_in[1];
  const float* scorer = (const float*)d_in[2];
  int F = in_sizes[2];      // 256
  int N = in_sizes[0] / F;  // 100000
  int k = out_size / F;     // 2000

  // keys live in d_out (N*4 = 400KB << 2MB); k5 overwrites all of d_out.
  uint32_t* keys = (uint32_t*)d_out;
  uint32_t* oidx = (uint32_t*)d_ws;  // 8KB

  k1_scores<<<(N + 31) / 32, 256, 0, stream>>>(embs, mask, scorer, keys, N);
  kSel<<<SELB, 1024, 0, stream>>>(keys, oidx, N, k);
  k5_gather<<<dim3((k + 15) / 16, 2), 256, 0, stream>>>(embs, oidx, (float*)d_out, k);
}

// Round 16
// 45.228 us; speedup vs baseline: 2.3621x; 2.3621x over previous
//
#include <hip/hip_runtime.h>
#include <stdint.h>

// ---------------------------------------------------------------------------
// TopK: scores = (embs @ scorer)/sum(scorer) + mask; top-k rows; out = rows^T
// Ordering matches numpy/OpenBLAS sgemv_t fp32 bits exactly (verified
// R3/R5/R6/R8/R10-R15, absmax=0): per row, 8 mod-8 fma chains (chain c sums
// elements c, c+8, ... ascending), reduced as
// ((L0+L4)+(L1+L5))+((L2+L6)+(L3+L7)), realized as 8 threads/row +
// shfl_xor pair-sums (bitwise-commutative adds).
// R16 = R11 (best: 48.1us; k1~17us = HBM floor) + kHistFind diet:
//   - NBINS 4096 (R12-verified radix), halves hist work
//   - no partials round-trip: blocks atomicAdd pre-aggregated LDS hists into
//     ONE global hist (<=8 adders/address x 4096 addresses = spread, safe)
//   - RELAXED poll + single ACQUIRE after: one L2 invalidate, not hundreds
// Lessons enforced: no multi-block waiting (R9/R10/R12); publish-and-exit +
// single poller only (R11); no few-block full-N scans (R15: ~10us/100K keys).
// Pipeline: k1 -> kHistFind -> k3 compact -> k4 rank -> k5 gather/transpose.
// d_out holds keys (k5 overwrites all). ws: hdr 1KB | hist 16KB | ckey 16KB
// | cidx 16KB | oidx 8KB = 57KB.
// ---------------------------------------------------------------------------

#define NBINS 4096   // 12-bit radix: sign + exp(8) + mantissa(3)
#define BIN_SHIFT 20
#define CAP 4096     // candidates: k + boundary bin (~900) << CAP (R12 ok)
#define HPARTS 8

__device__ __forceinline__ uint32_t f2key(float f) {
  uint32_t b = __float_as_uint(f);
  return (b & 0x80000000u) ? ~b : (b | 0x80000000u);
}

// ---- kernel 1: 32 rows/block, 8 threads/row (one mod-8 chain each) --------
// R11 verbatim + block 0 zeroes hdr and the global hist.
__global__ __launch_bounds__(256) void k1_scores(
    const float* __restrict__ embs, const float* __restrict__ mask,
    const float* __restrict__ scorer, uint32_t* __restrict__ keys,
    uint32_t* __restrict__ hdr, uint32_t* __restrict__ hist, int N) {
  __shared__ float tile[32 * 132];
  __shared__ float sw[256];
  __shared__ float Ssh;
  int t = threadIdx.x;
  int r0 = blockIdx.x * 32;
  if (blockIdx.x == 0) {
    if (t < 16) hdr[t] = 0u;  // [0]=B [1]=cum [2]=cand ctr [8]=flag
    for (int i = t; i < NBINS; i += 256) hist[i] = 0u;
  }
  sw[t] = scorer[t];  // F == 256
  __syncthreads();
  if (t < 64) {
    double s = 0.0;
    for (int j = t; j < 256; j += 64) s += (double)sw[j];
#pragma unroll
    for (int off = 32; off >= 1; off >>= 1) s += __shfl_xor(s, off, 64);
    if (t == 0) Ssh = (float)s;  // f64 sum: order-independent at f32 grain
  }
  __syncthreads();
  float S = Ssh;
  int r = t >> 3, c = t & 7;
  float acc = 0.f;
  const float4* e4 = (const float4*)embs;
#pragma unroll
  for (int ch = 0; ch < 2; ++ch) {
    if (ch) __syncthreads();  // previous chunk's LDS reads complete
#pragma unroll
    for (int m = 0; m < 4; ++m) {      // 4*256 = 1024 f4 = 32 rows x 32 f4
      int flat = m * 256 + t;
      int rr = flat >> 5;              // 0..31
      int cc4 = flat & 31;             // 0..31
      int row = r0 + rr;
      float4 v = make_float4(0.f, 0.f, 0.f, 0.f);
      if (row < N) v = e4[(size_t)row * 64 + ch * 32 + cc4];  // 512B segs
      float* dst = &tile[rr * 132 + cc4 * 4];
      dst[0] = v.x; dst[1] = v.y; dst[2] = v.z; dst[3] = v.w;
    }
    __syncthreads();
#pragma unroll
    for (int sl = 0; sl < 16; ++sl) {  // ascending k within the chain
      acc = fmaf(tile[r * 132 + c + 8 * sl], sw[ch * 128 + c + 8 * sl], acc);
    }
  }
  // exact OpenBLAS bracket via commutative pair-sums (lanes stay in-row):
  float m1 = acc + __shfl_xor(acc, 4, 64);  // L_c + L_{c+4}
  float p1 = m1 + __shfl_xor(m1, 1, 64);    // (m0+m1) / (m2+m3)
  float dot = p1 + __shfl_xor(p1, 2, 64);   // ((m0+m1)+(m2+m3))
  int row = r0 + r;
  if (c == 0 && row < N) {
    float score = dot / S + mask[row];
    keys[row] = f2key(score);
  }
}

// ---- kernel HistFind: LDS hists -> spread global atomics; block0 finds B --
__global__ __launch_bounds__(1024) void kHistFind(
    const uint32_t* __restrict__ keys, uint32_t* __restrict__ hist,
    uint32_t* __restrict__ hdr, int N, int k) {
  __shared__ uint32_t h[2][NBINS];  // 32 KB
  __shared__ uint32_t wtot[16], wsuf[16];
  int t = threadIdx.x, bid = blockIdx.x;
  int lane = t & 63, wave = t >> 6;

  // --- phase A: this block's LDS hist over its slice ---
  for (int i = t; i < 2 * NBINS; i += 1024) ((uint32_t*)h)[i] = 0u;
  __syncthreads();
  int per = (N + HPARTS - 1) / HPARTS;
  int lo = bid * per;
  int hi = lo + per; if (hi > N) hi = N;
  int sub = (t >> 7) & 1;
  int n4 = (hi - lo) >> 2;
  const uint4* q4 = (const uint4*)(keys + lo);
  for (int i = t; i < n4; i += 1024) {
    uint4 v = q4[i];
    atomicAdd(&h[sub][v.x >> BIN_SHIFT], 1u);
    atomicAdd(&h[sub][v.y >> BIN_SHIFT], 1u);
    atomicAdd(&h[sub][v.z >> BIN_SHIFT], 1u);
    atomicAdd(&h[sub][v.w >> BIN_SHIFT], 1u);
  }
  for (int i = lo + (n4 << 2) + t; i < hi; i += 1024)
    atomicAdd(&h[sub][keys[i] >> BIN_SHIFT], 1u);
  __syncthreads();
  // --- flush pre-aggregated counts: <=8 adders per address, spread ---
  for (int i = t; i < NBINS; i += 1024) {
    uint32_t v = h[0][i] + h[1][i];
    if (v) atomicAdd(&hist[i], v);
  }
  __syncthreads();
  if (t == 0) {
    __threadfence();  // order hist RMWs before flag (agent scope)
    __hip_atomic_fetch_add(&hdr[8], 1u, __ATOMIC_ACQ_REL, __HIP_MEMORY_SCOPE_AGENT);
  }
  if (bid != 0) return;  // publish-and-exit (R11 lesson)

  // --- single poller, RELAXED loop + one ACQUIRE (R15 invalidate lesson) ---
  if (t == 0) {
    while (__hip_atomic_load(&hdr[8], __ATOMIC_RELAXED, __HIP_MEMORY_SCOPE_AGENT) < HPARTS)
      __builtin_amdgcn_s_sleep(8);
    (void)__hip_atomic_load(&hdr[8], __ATOMIC_ACQUIRE, __HIP_MEMORY_SCOPE_AGENT);
  }
  __syncthreads();

  // --- phase B: 4 bins/thread + suffix scan (R12-verified structure) ---
  uint4 a = ((const uint4*)hist)[t];
  uint32_t rb[4] = {a.x, a.y, a.z, a.w};
  uint32_t p4 = rb[0] + rb[1] + rb[2] + rb[3];
  uint32_t x = p4;  // wave-internal inclusive suffix scan
#pragma unroll
  for (int off = 1; off < 64; off <<= 1) {
    uint32_t v = __shfl_down(x, off, 64);
    if (lane + off < 64) x += v;
  }
  if (lane == 0) wtot[wave] = x;
  __syncthreads();
  if (t < 16) {
    uint32_t y = wtot[t];
#pragma unroll
    for (int off = 1; off < 16; off <<= 1) {
      uint32_t v = __shfl_down(y, off, 64);
      if (t + off < 16) y += v;
    }
    wsuf[t] = y - wtot[t];  // sum of waves after t
  }
  __syncthreads();
  uint32_t St = x + wsuf[wave];  // count(bin >= 4t)
  uint32_t above = St - p4;      // count(bin >= 4(t+1))
  if (above < (uint32_t)k && St >= (uint32_t)k) {  // unique thread
    uint32_t cum = above;
#pragma unroll
    for (int jj = 3; jj >= 0; --jj) {
      if (cum + rb[jj] >= (uint32_t)k) { hdr[0] = (uint32_t)(t * 4 + jj); hdr[1] = cum; break; }
      cum += rb[jj];
    }
  }
}

// ---- kernel 3: compact candidates (bin >= B), block-aggregated atomic ------
__global__ __launch_bounds__(256) void k3_compact(
    const uint32_t* __restrict__ keys, const uint32_t* __restrict__ hdr,
    uint32_t* __restrict__ ckey, uint32_t* __restrict__ cidx,
    uint32_t* __restrict__ counter, int N) {
  __shared__ uint32_t wcnt[4];
  __shared__ uint32_t wbase[4];
  __shared__ uint32_t blkbase;
  int i = blockIdx.x * 256 + threadIdx.x;
  int wave = threadIdx.x >> 6, lane = threadIdx.x & 63;
  uint32_t B = hdr[0];
  bool pred = false;
  uint32_t key = 0;
  if (i < N) {
    key = keys[i];
    pred = (key >> BIN_SHIFT) >= B;
  }
  unsigned long long ball = __ballot(pred);
  uint32_t prefix = (uint32_t)__popcll(ball & ((1ull << lane) - 1ull));
  if (lane == 0) wcnt[wave] = (uint32_t)__popcll(ball);
  __syncthreads();
  if (threadIdx.x == 0) {
    uint32_t tot = wcnt[0] + wcnt[1] + wcnt[2] + wcnt[3];
    blkbase = tot ? atomicAdd(counter, tot) : 0u;
    wbase[0] = 0;
    wbase[1] = wcnt[0];
    wbase[2] = wcnt[0] + wcnt[1];
    wbase[3] = wcnt[0] + wcnt[1] + wcnt[2];
  }
  __syncthreads();
  if (pred) {
    uint32_t pos = blkbase + wbase[wave] + prefix;
    if (pos < CAP) { ckey[pos] = key; cidx[pos] = (uint32_t)i; }
  }
}

// ---- kernel 4: exact rank, 4 candidates/wave, 16/block --------------------
__global__ __launch_bounds__(256) void k4_rank(
    const uint32_t* __restrict__ ckey, const uint32_t* __restrict__ cidx,
    const uint32_t* __restrict__ hdr, uint32_t* __restrict__ oidx, int k) {
  __shared__ uint32_t lk[CAP];
  __shared__ uint32_t li[CAP];
  uint32_t C = hdr[2];
  if (C > CAP) C = CAP;
  uint32_t base = blockIdx.x * 16u;
  if (base >= C) return;
  for (uint32_t j = threadIdx.x; j < C; j += 256u) {
    lk[j] = ckey[j];
    li[j] = cidx[j];
  }
  __syncthreads();
  int wave = threadIdx.x >> 6, lane = threadIdx.x & 63;
  uint32_t g0 = base + wave * 4u;
  uint32_t mk[4], mi[4], cnt[4];
#pragma unroll
  for (int q = 0; q < 4; ++q) {
    uint32_t g = g0 + q;
    bool valid = g < C;
    mk[q] = valid ? lk[g] : 0u;
    mi[q] = valid ? li[g] : 0xFFFFFFFFu;
    cnt[q] = 0u;
  }
  for (uint32_t j = lane; j < C; j += 64u) {
    uint32_t kj = lk[j], ij = li[j];
#pragma unroll
    for (int q = 0; q < 4; ++q)
      cnt[q] += (kj > mk[q] || (kj == mk[q] && ij < mi[q])) ? 1u : 0u;
  }
#pragma unroll
  for (int q = 0; q < 4; ++q) {
#pragma unroll
    for (int off = 32; off >= 1; off >>= 1) cnt[q] += __shfl_xor(cnt[q], off, 64);
  }
  if (lane == 0) {
#pragma unroll
    for (int q = 0; q < 4; ++q) {
      uint32_t g = g0 + q;
      if (g < C && cnt[q] < (uint32_t)k) oidx[cnt[q]] = mi[q];
    }
  }
}

// ---- kernel 5: gather + transpose; 16 ranks x 128 feats per block ----------
__global__ __launch_bounds__(256) void k5_gather(
    const float* __restrict__ embs, const uint32_t* __restrict__ oidx,
    float* __restrict__ out, int k) {
  __shared__ float tile[16 * 132];
  __shared__ uint32_t sidx[16];
  int t = threadIdx.x;
  int r0 = blockIdx.x * 16;
  int fb = blockIdx.y * 128;
  if (t < 16) sidx[t] = (r0 + t < k) ? oidx[r0 + t] : 0u;
  __syncthreads();
  const float4* e4 = (const float4*)embs;
#pragma unroll
  for (int m = 0; m < 2; ++m) {      // 2*256 = 512 f4 = 16 rows x 32 f4
    int flat = m * 256 + t;
    int rr = flat >> 5;
    int cc4 = flat & 31;
    float4 v = e4[(size_t)sidx[rr] * 64 + (fb >> 2) + cc4];
    float* dst = &tile[rr * 132 + cc4 * 4];
    dst[0] = v.x; dst[1] = v.y; dst[2] = v.z; dst[3] = v.w;
  }
  __syncthreads();
  int fl = t >> 1;   // 0..127 local feature
  int rq = t & 1;    // which 8-rank group
  float v[8];
#pragma unroll
  for (int i = 0; i < 8; ++i) v[i] = tile[(rq * 8 + i) * 132 + fl];
  size_t obase = (size_t)(fb + fl) * k + r0 + rq * 8;
  if (((k & 3) == 0) && (r0 + rq * 8 + 7 < k)) {
    *(float4*)(out + obase) = make_float4(v[0], v[1], v[2], v[3]);
    *(float4*)(out + obase + 4) = make_float4(v[4], v[5], v[6], v[7]);
  } else {
#pragma unroll
    for (int i = 0; i < 8; ++i)
      if (r0 + rq * 8 + i < k) out[obase + i] = v[i];
  }
}

extern "C" void kernel_launch(void* const* d_in, const int* in_sizes, int n_in,
                              void* d_out, int out_size, void* d_ws, size_t ws_size,
                              hipStream_t stream) {
  const float* embs = (const float*)d_in[0];
  const float* mask = (const float*)d_in[1];
  const float* scorer = (const float*)d_in[2];
  int F = in_sizes[2];      // 256
  int N = in_sizes[0] / F;  // 100000
  int k = out_size / F;     // 2000

  // keys live in d_out (N*4 = 400KB << 2MB); k5 overwrites all of d_out.
  uint32_t* keys = (uint32_t*)d_out;

  char* ws = (char*)d_ws;
  uint32_t* hdr = (uint32_t*)ws;                       // 1KB
  uint32_t* hist = (uint32_t*)(ws + 1024);             // 16KB
  uint32_t* ckey = (uint32_t*)(ws + 1024 + NBINS * 4); // 16KB
  uint32_t* cidx = ckey + CAP;                         // 16KB
  uint32_t* oidx = cidx + CAP;                         // 8KB

  k1_scores<<<(N + 31) / 32, 256, 0, stream>>>(embs, mask, scorer, keys, hdr, hist, N);
  kHistFind<<<HPARTS, 1024, 0, stream>>>(keys, hist, hdr, N, k);
  k3_compact<<<(N + 255) / 256, 256, 0, stream>>>(keys, hdr, ckey, cidx, &hdr[2], N);
  k4_rank<<<(CAP + 15) / 16, 256, 0, stream>>>(ckey, cidx, hdr, oidx, k);
  k5_gather<<<dim3((k + 15) / 16, 2), 256, 0, stream>>>(embs, oidx, (float*)d_out, k);
}

// Round 17
// 43.133 us; speedup vs baseline: 2.4769x; 1.0486x over previous
//
#include <hip/hip_runtime.h>
#include <stdint.h>

// ---------------------------------------------------------------------------
// TopK: scores = (embs @ scorer)/sum(scorer) + mask; top-k rows; out = rows^T
// Ordering matches numpy/OpenBLAS sgemv_t fp32 bits exactly (verified
// R3/R5/R6/R8/R10-R16, absmax=0): per row, 8 mod-8 fma chains (chain c sums
// elements c, c+8, ... ascending), reduced as
// ((L0+L4)+(L1+L5))+((L2+L6)+(L3+L7)), realized as 8 threads/row +
// shfl_xor pair-sums (bitwise-commutative adds).
// R17 = R16 with kHistFind+k3 merged into kSel (98 blocks x 1024):
//   blocks 0-7: LDS hist over 1/8 slice -> spread-atomic flush -> flag1.
//   block 0: RELAXED-poll flag1 + 1 ACQUIRE -> suffix-scan -> B -> flag2.
//   all blocks: RELAXED-poll flag2 + 1 ACQUIRE (R16-validated primitive;
//   97 pollers x s_sleep(16) = ~0.1 polls/ns, read-shared line), then
//   compact own 1024-key slice (R12-verified 16-wave ballot body).
// Gap arithmetic (R16): dependent-launch gaps cost ~3.5-4us each; this
// merge removes one gap + one launch. Pipeline: k1 -> kSel -> k4 -> k5.
// d_out holds keys (k5 overwrites all). ws: hdr 1KB | hist 16KB | ckey 16KB
// | cidx 16KB | oidx 8KB = 57KB.
// ---------------------------------------------------------------------------

#define NBINS 4096   // 12-bit radix: sign + exp(8) + mantissa(3)
#define BIN_SHIFT 20
#define CAP 4096     // candidates: k + boundary bin (~900) << CAP (R12/R16 ok)
#define HPARTS 8

__device__ __forceinline__ uint32_t f2key(float f) {
  uint32_t b = __float_as_uint(f);
  return (b & 0x80000000u) ? ~b : (b | 0x80000000u);
}

// ---- kernel 1: 32 rows/block, 8 threads/row (one mod-8 chain each) --------
// R16 verbatim: block 0 zeroes hdr + global hist.
__global__ __launch_bounds__(256) void k1_scores(
    const float* __restrict__ embs, const float* __restrict__ mask,
    const float* __restrict__ scorer, uint32_t* __restrict__ keys,
    uint32_t* __restrict__ hdr, uint32_t* __restrict__ hist, int N) {
  __shared__ float tile[32 * 132];
  __shared__ float sw[256];
  __shared__ float Ssh;
  int t = threadIdx.x;
  int r0 = blockIdx.x * 32;
  if (blockIdx.x == 0) {
    if (t < 16) hdr[t] = 0u;  // [0]=B [1]=cum [2]=cand ctr [8]=flag1 [9]=flag2
    for (int i = t; i < NBINS; i += 256) hist[i] = 0u;
  }
  sw[t] = scorer[t];  // F == 256
  __syncthreads();
  if (t < 64) {
    double s = 0.0;
    for (int j = t; j < 256; j += 64) s += (double)sw[j];
#pragma unroll
    for (int off = 32; off >= 1; off >>= 1) s += __shfl_xor(s, off, 64);
    if (t == 0) Ssh = (float)s;  // f64 sum: order-independent at f32 grain
  }
  __syncthreads();
  float S = Ssh;
  int r = t >> 3, c = t & 7;
  float acc = 0.f;
  const float4* e4 = (const float4*)embs;
#pragma unroll
  for (int ch = 0; ch < 2; ++ch) {
    if (ch) __syncthreads();  // previous chunk's LDS reads complete
#pragma unroll
    for (int m = 0; m < 4; ++m) {      // 4*256 = 1024 f4 = 32 rows x 32 f4
      int flat = m * 256 + t;
      int rr = flat >> 5;              // 0..31
      int cc4 = flat & 31;             // 0..31
      int row = r0 + rr;
      float4 v = make_float4(0.f, 0.f, 0.f, 0.f);
      if (row < N) v = e4[(size_t)row * 64 + ch * 32 + cc4];  // 512B segs
      float* dst = &tile[rr * 132 + cc4 * 4];
      dst[0] = v.x; dst[1] = v.y; dst[2] = v.z; dst[3] = v.w;
    }
    __syncthreads();
#pragma unroll
    for (int sl = 0; sl < 16; ++sl) {  // ascending k within the chain
      acc = fmaf(tile[r * 132 + c + 8 * sl], sw[ch * 128 + c + 8 * sl], acc);
    }
  }
  // exact OpenBLAS bracket via commutative pair-sums (lanes stay in-row):
  float m1 = acc + __shfl_xor(acc, 4, 64);  // L_c + L_{c+4}
  float p1 = m1 + __shfl_xor(m1, 1, 64);    // (m0+m1) / (m2+m3)
  float dot = p1 + __shfl_xor(p1, 2, 64);   // ((m0+m1)+(m2+m3))
  int row = r0 + r;
  if (c == 0 && row < N) {
    float score = dot / S + mask[row];
    keys[row] = f2key(score);
  }
}

// ---- kernel Sel: hist(8 blocks) -> B(block0) -> compact(all 98 blocks) ----
// hdr: [0]=B [1]=cumAbove [2]=cand ctr [8]=flag1 [9]=flag2
__global__ __launch_bounds__(1024) void kSel(
    const uint32_t* __restrict__ keys, uint32_t* __restrict__ hist,
    uint32_t* __restrict__ hdr, uint32_t* __restrict__ ckey,
    uint32_t* __restrict__ cidx, int N, int k) {
  __shared__ uint32_t h[2][NBINS];  // 32 KB (workers); reused flags below
  __shared__ uint32_t wtot[16], wsuf[16];
  __shared__ uint32_t wcnt[16], wbase[16];
  __shared__ uint32_t blkbase;
  int t = threadIdx.x, bid = blockIdx.x;
  int lane = t & 63, wave = t >> 6;

  // --- phase A: 8 worker blocks build + flush partial hists ---
  if (bid < HPARTS) {
    for (int i = t; i < 2 * NBINS; i += 1024) ((uint32_t*)h)[i] = 0u;
    __syncthreads();
    int per = (N + HPARTS - 1) / HPARTS;
    int lo = bid * per;
    int hi = lo + per; if (hi > N) hi = N;
    int sub = (t >> 7) & 1;
    int n4 = (hi - lo) >> 2;
    const uint4* q4 = (const uint4*)(keys + lo);
    for (int i = t; i < n4; i += 1024) {
      uint4 v = q4[i];
      atomicAdd(&h[sub][v.x >> BIN_SHIFT], 1u);
      atomicAdd(&h[sub][v.y >> BIN_SHIFT], 1u);
      atomicAdd(&h[sub][v.z >> BIN_SHIFT], 1u);
      atomicAdd(&h[sub][v.w >> BIN_SHIFT], 1u);
    }
    for (int i = lo + (n4 << 2) + t; i < hi; i += 1024)
      atomicAdd(&h[sub][keys[i] >> BIN_SHIFT], 1u);
    __syncthreads();
    // flush pre-aggregated counts: <=8 adders per address, spread (R16 ok)
    for (int i = t; i < NBINS; i += 1024) {
      uint32_t v = h[0][i] + h[1][i];
      if (v) atomicAdd(&hist[i], v);
    }
    __syncthreads();
    if (t == 0) {
      __threadfence();  // order hist RMWs before flag1 (agent scope)
      __hip_atomic_fetch_add(&hdr[8], 1u, __ATOMIC_ACQ_REL, __HIP_MEMORY_SCOPE_AGENT);
    }
  }

  // --- phase B: block 0 computes B, publishes flag2 ---
  if (bid == 0) {
    if (t == 0) {
      while (__hip_atomic_load(&hdr[8], __ATOMIC_RELAXED, __HIP_MEMORY_SCOPE_AGENT) < HPARTS)
        __builtin_amdgcn_s_sleep(8);
      (void)__hip_atomic_load(&hdr[8], __ATOMIC_ACQUIRE, __HIP_MEMORY_SCOPE_AGENT);
    }
    __syncthreads();
    uint4 a = ((const uint4*)hist)[t];  // 4 bins/thread
    uint32_t rb[4] = {a.x, a.y, a.z, a.w};
    uint32_t p4 = rb[0] + rb[1] + rb[2] + rb[3];
    uint32_t x = p4;  // wave-internal inclusive suffix scan
#pragma unroll
    for (int off = 1; off < 64; off <<= 1) {
      uint32_t v = __shfl_down(x, off, 64);
      if (lane + off < 64) x += v;
    }
    if (lane == 0) wtot[wave] = x;
    __syncthreads();
    if (t < 16) {
      uint32_t y = wtot[t];
#pragma unroll
      for (int off = 1; off < 16; off <<= 1) {
        uint32_t v = __shfl_down(y, off, 64);
        if (t + off < 16) y += v;
      }
      wsuf[t] = y - wtot[t];  // sum of waves after t
    }
    __syncthreads();
    uint32_t St = x + wsuf[wave];  // count(bin >= 4t)
    uint32_t above = St - p4;      // count(bin >= 4(t+1))
    if (above < (uint32_t)k && St >= (uint32_t)k) {  // unique thread
      uint32_t cum = above;
#pragma unroll
      for (int jj = 3; jj >= 0; --jj) {
        if (cum + rb[jj] >= (uint32_t)k) {
          hdr[0] = (uint32_t)(t * 4 + jj);
          hdr[1] = cum;
          __threadfence();  // publish B before flag2
          __hip_atomic_fetch_add(&hdr[9], 1u, __ATOMIC_ACQ_REL, __HIP_MEMORY_SCOPE_AGENT);
          break;
        }
        cum += rb[jj];
      }
    }
    __syncthreads();
  } else {
    // all other blocks: RELAXED-poll flag2 + single ACQUIRE (R16 primitive)
    if (t == 0) {
      while (__hip_atomic_load(&hdr[9], __ATOMIC_RELAXED, __HIP_MEMORY_SCOPE_AGENT) < 1u)
        __builtin_amdgcn_s_sleep(16);
      (void)__hip_atomic_load(&hdr[9], __ATOMIC_ACQUIRE, __HIP_MEMORY_SCOPE_AGENT);
    }
    __syncthreads();
  }
  uint32_t B = hdr[0];

  // --- phase C: compact own 1024-key slice (R12-verified 16-wave body) ---
  int i = bid * 1024 + t;
  bool pred = false;
  uint32_t key = 0;
  if (i < N) {
    key = keys[i];
    pred = (key >> BIN_SHIFT) >= B;
  }
  unsigned long long ball = __ballot(pred);
  uint32_t prefix = (uint32_t)__popcll(ball & ((1ull << lane) - 1ull));
  if (lane == 0) wcnt[wave] = (uint32_t)__popcll(ball);
  __syncthreads();
  if (t == 0) {
    uint32_t tot = 0;
#pragma unroll
    for (int w = 0; w < 16; ++w) { wbase[w] = tot; tot += wcnt[w]; }
    blkbase = tot ? atomicAdd(&hdr[2], tot) : 0u;  // 98 RMWs total (safe)
  }
  __syncthreads();
  if (pred) {
    uint32_t pos = blkbase + wbase[wave] + prefix;
    if (pos < CAP) { ckey[pos] = key; cidx[pos] = (uint32_t)i; }
  }
}

// ---- kernel 4: exact rank, 4 candidates/wave, 16/block --------------------
__global__ __launch_bounds__(256) void k4_rank(
    const uint32_t* __restrict__ ckey, const uint32_t* __restrict__ cidx,
    const uint32_t* __restrict__ hdr, uint32_t* __restrict__ oidx, int k) {
  __shared__ uint32_t lk[CAP];
  __shared__ uint32_t li[CAP];
  uint32_t C = hdr[2];
  if (C > CAP) C = CAP;
  uint32_t base = blockIdx.x * 16u;
  if (base >= C) return;
  for (uint32_t j = threadIdx.x; j < C; j += 256u) {
    lk[j] = ckey[j];
    li[j] = cidx[j];
  }
  __syncthreads();
  int wave = threadIdx.x >> 6, lane = threadIdx.x & 63;
  uint32_t g0 = base + wave * 4u;
  uint32_t mk[4], mi[4], cnt[4];
#pragma unroll
  for (int q = 0; q < 4; ++q) {
    uint32_t g = g0 + q;
    bool valid = g < C;
    mk[q] = valid ? lk[g] : 0u;
    mi[q] = valid ? li[g] : 0xFFFFFFFFu;
    cnt[q] = 0u;
  }
  for (uint32_t j = lane; j < C; j += 64u) {
    uint32_t kj = lk[j], ij = li[j];
#pragma unroll
    for (int q = 0; q < 4; ++q)
      cnt[q] += (kj > mk[q] || (kj == mk[q] && ij < mi[q])) ? 1u : 0u;
  }
#pragma unroll
  for (int q = 0; q < 4; ++q) {
#pragma unroll
    for (int off = 32; off >= 1; off >>= 1) cnt[q] += __shfl_xor(cnt[q], off, 64);
  }
  if (lane == 0) {
#pragma unroll
    for (int q = 0; q < 4; ++q) {
      uint32_t g = g0 + q;
      if (g < C && cnt[q] < (uint32_t)k) oidx[cnt[q]] = mi[q];
    }
  }
}

// ---- kernel 5: gather + transpose; 16 ranks x 128 feats per block ----------
__global__ __launch_bounds__(256) void k5_gather(
    const float* __restrict__ embs, const uint32_t* __restrict__ oidx,
    float* __restrict__ out, int k) {
  __shared__ float tile[16 * 132];
  __shared__ uint32_t sidx[16];
  int t = threadIdx.x;
  int r0 = blockIdx.x * 16;
  int fb = blockIdx.y * 128;
  if (t < 16) sidx[t] = (r0 + t < k) ? oidx[r0 + t] : 0u;
  __syncthreads();
  const float4* e4 = (const float4*)embs;
#pragma unroll
  for (int m = 0; m < 2; ++m) {      // 2*256 = 512 f4 = 16 rows x 32 f4
    int flat = m * 256 + t;
    int rr = flat >> 5;
    int cc4 = flat & 31;
    float4 v = e4[(size_t)sidx[rr] * 64 + (fb >> 2) + cc4];
    float* dst = &tile[rr * 132 + cc4 * 4];
    dst[0] = v.x; dst[1] = v.y; dst[2] = v.z; dst[3] = v.w;
  }
  __syncthreads();
  int fl = t >> 1;   // 0..127 local feature
  int rq = t & 1;    // which 8-rank group
  float v[8];
#pragma unroll
  for (int i = 0; i < 8; ++i) v[i] = tile[(rq * 8 + i) * 132 + fl];
  size_t obase = (size_t)(fb + fl) * k + r0 + rq * 8;
  if (((k & 3) == 0) && (r0 + rq * 8 + 7 < k)) {
    *(float4*)(out + obase) = make_float4(v[0], v[1], v[2], v[3]);
    *(float4*)(out + obase + 4) = make_float4(v[4], v[5], v[6], v[7]);
  } else {
#pragma unroll
    for (int i = 0; i < 8; ++i)
      if (r0 + rq * 8 + i < k) out[obase + i] = v[i];
  }
}

extern "C" void kernel_launch(void* const* d_in, const int* in_sizes, int n_in,
                              void* d_out, int out_size, void* d_ws, size_t ws_size,
                              hipStream_t stream) {
  const float* embs = (const float*)d_in[0];
  const float* mask = (const float*)d_in[1];
  const float* scorer = (const float*)d_in[2];
  int F = in_sizes[2];      // 256
  int N = in_sizes[0] / F;  // 100000
  int k = out_size / F;     // 2000

  // keys live in d_out (N*4 = 400KB << 2MB); k5 overwrites all of d_out.
  uint32_t* keys = (uint32_t*)d_out;

  char* ws = (char*)d_ws;
  uint32_t* hdr = (uint32_t*)ws;                       // 1KB
  uint32_t* hist = (uint32_t*)(ws + 1024);             // 16KB
  uint32_t* ckey = (uint32_t*)(ws + 1024 + NBINS * 4); // 16KB
  uint32_t* cidx = ckey + CAP;                         // 16KB
  uint32_t* oidx = cidx + CAP;                         // 8KB

  int nsel = (N + 1023) / 1024;  // 98 blocks
  k1_scores<<<(N + 31) / 32, 256, 0, stream>>>(embs, mask, scorer, keys, hdr, hist, N);
  kSel<<<nsel, 1024, 0, stream>>>(keys, hist, hdr, ckey, cidx, N, k);
  k4_rank<<<(CAP + 15) / 16, 256, 0, stream>>>(ckey, cidx, hdr, oidx, k);
  k5_gather<<<dim3((k + 15) / 16, 2), 256, 0, stream>>>(embs, oidx, (float*)d_out, k);
}